// Round 6
// baseline (215.449 us; speedup 1.0000x reference)
//
#include <hip/hip_runtime.h>
#include <math.h>

#define HH 2048
#define WW 2048
#define PLANE 4194304        // HH*WW
#define TPITCH 44
#define TPP (26*TPITCH)      // 1144 floats per plane

// ws layout (bytes):
// 0     : float gwin[11]
// 64    : (unused)
// 128   : double lG[4]
// 256   : double lYpart[4*528]   (16896 B)
// 17408 : double qpart[8192]     (65536 B)

__device__ inline double wave_red(double v) {
#pragma unroll
  for (int o = 32; o > 0; o >>= 1) v += __shfl_down(v, o, 64);
  return v;
}

__global__ void k0_window(float* gwin) {
  if (threadIdx.x == 0) {
    double e[11], s = 0.0;
    double sig = 11.0 / 6.0;
    for (int i = 0; i < 11; ++i) {
      double x = (double)(i - 5);
      e[i] = exp(-(x * x) / (2.0 * sig * sig));
      s += e[i];
    }
    for (int i = 0; i < 11; ++i) gwin[i] = (float)(e[i] / s);
  }
}

// k1: lY partial sums (unchanged; ~18 us).
__global__ __launch_bounds__(256) void k1_lY(const float* __restrict__ Ys,
                                             const float* __restrict__ gwin,
                                             double* __restrict__ lYpart) {
  int bid = blockIdx.x;
  int tid = threadIdx.x;
  double acc = 0.0;
  __shared__ float P[12];
  __shared__ double red[4];

  if (bid < 2048) {
    const float4* __restrict__ p = (const float4*)Ys;
    int base = bid * 6144 + tid;
#pragma unroll 1
    for (int gblk = 0; gblk < 3; ++gblk) {
      float ax = 0.f, ay = 0.f;
#pragma unroll
      for (int u = 0; u < 8; ++u) {
        float4 v = p[base + (gblk * 8 + u) * 256];
        ax += v.x + v.z;
        ay += v.y + v.w;
      }
      acc += (double)(ax + ay);
    }
  } else {
    int b = bid - 2048;             // 0..63
    int k = b >> 4, sub = b & 15;
    if (tid == 0) {
      float s = 0.f;
      for (int i = 0; i < 12; ++i) { P[i] = s; if (i < 11) s += gwin[i]; }
    }
    __syncthreads();
    const float4* __restrict__ Yk4 = (const float4*)(Ys + (size_t)k * 3 * PLANE);
    auto covP = [&](int r) -> float {
      if (r >= 5 && r <= 2042) return 1.0f;
      int dhi = r + 5; if (dhi > 10) dhi = 10;
      int dlo = r - 2042; if (dlo < 0) dlo = 0;
      return P[dhi + 1] - P[dlo];
    };
#pragma unroll 1
    for (int t = sub * 256 + tid; t < 39816; t += 4096) {
      int ch, row, g4;
      if (t < 15360) {
        ch = t / 5120;
        int r = (t % 5120) / 512;
        g4 = t & 511;
        row = (r < 5) ? r : r + 2038;
      } else {
        int u = t - 15360;
        ch = u / 8152;
        int rem = u % 8152;
        row = 5 + (rem >> 2);
        int gi = rem & 3;
        g4 = (gi < 2) ? gi : 508 + gi;
      }
      float4 v = Yk4[ch * 1048576 + row * 512 + g4];
      float cy = covP(row);
      int x0 = g4 << 2;
      float w0 = cy * covP(x0)     - 1.0f;
      float w1 = cy * covP(x0 + 1) - 1.0f;
      float w2 = cy * covP(x0 + 2) - 1.0f;
      float w3 = cy * covP(x0 + 3) - 1.0f;
      acc += (double)(w0 * v.x + w1 * v.y + w2 * v.z + w3 * v.w);
    }
  }

  acc = wave_red(acc);
  int lane = tid & 63, wid = tid >> 6;
  __syncthreads();
  if (lane == 0) red[wid] = acc;
  __syncthreads();
  if (tid == 0) {
    double tot = red[0] + red[1] + red[2] + red[3];
    if (bid < 2048) {
      int k = bid >> 9;
      lYpart[k * 528 + (bid & 511)] = tot;
    } else {
      int b = bid - 2048;
      lYpart[(b >> 4) * 528 + 512 + (b & 15)] = tot;
    }
  }
}

__global__ __launch_bounds__(256) void k2a_lG(const double* __restrict__ lYpart,
                                              double* __restrict__ lG) {
  __shared__ double red[4];
  for (int k = 0; k < 4; ++k) {
    const double* p = lYpart + k * 528;
    double v = p[threadIdx.x] + p[256 + threadIdx.x];
    if (threadIdx.x < 16) v += p[512 + threadIdx.x];
    v = wave_red(v);
    int lane = threadIdx.x & 63, wid = threadIdx.x >> 6;
    if (lane == 0) red[wid] = v;
    __syncthreads();
    if (threadIdx.x == 0) {
      double tot = red[0] + red[1] + red[2] + red[3];
      double lY = tot * (1.0 / 12582912.0);
      double d = lY - 0.5;
      lG[k] = exp(-(d * d) / 0.08);
    }
    __syncthreads();
  }
}

// ---- H-blur: half-rows, load -> barrier -> compute+write (in-place safe).
// ALL threads must call (internal barrier). Window/outputs on named/const-idx
// regs only; taps read directly from gwin (SGPR).
template <int NP>
__device__ inline void hblur_planes(float* lds, int tid,
                                    const float* __restrict__ gw) {
  bool valid = tid < NP * 52;
  int half = 0, f = 0, row = 0;
  float w[28];
  float* rp = nullptr;
  if (valid) {
    half = tid / (NP * 26);
    int rem = tid - half * (NP * 26);
    f = rem / 26;
    row = rem - f * 26;
    rp = lds + f * TPP + row * TPITCH;
    const float* bp = rp + 16 * half;   // h0: px 0..27, h1: px 16..43
#pragma unroll
    for (int j = 0; j < 7; ++j) {
      float4 t = *(const float4*)(bp + 4 * j);
      w[4*j] = t.x; w[4*j+1] = t.y; w[4*j+2] = t.z; w[4*j+3] = t.w;
    }
  }
  __syncthreads();
  if (valid) {
    float o[18];
    if (half == 0) {
      // outputs px 4..21 (px 4,5 junk); wi = j-1+d, clamp low
#pragma unroll
      for (int j = 0; j < 18; ++j) {
        float s = 0.f;
#pragma unroll
        for (int d = 0; d < 11; ++d) {
          int wi = j - 1 + d; if (wi < 0) wi = 0;
          s += gw[d] * w[wi];
        }
        o[j] = s;
      }
      *(float4*)(rp + 4)  = make_float4(o[0], o[1], o[2], o[3]);
      *(float4*)(rp + 8)  = make_float4(o[4], o[5], o[6], o[7]);
      *(float4*)(rp + 12) = make_float4(o[8], o[9], o[10], o[11]);
      *(float4*)(rp + 16) = make_float4(o[12], o[13], o[14], o[15]);
      *(float2*)(rp + 20) = make_float2(o[16], o[17]);
    } else {
      // outputs px 22..39 (px 38,39 junk); wi = j+1+d, clamp high
#pragma unroll
      for (int j = 0; j < 18; ++j) {
        float s = 0.f;
#pragma unroll
        for (int d = 0; d < 11; ++d) {
          int wi = j + 1 + d; if (wi > 27) wi = 27;
          s += gw[d] * w[wi];
        }
        o[j] = s;
      }
      *(float2*)(rp + 22) = make_float2(o[0], o[1]);
      *(float4*)(rp + 24) = make_float4(o[2], o[3], o[4], o[5]);
      *(float4*)(rp + 28) = make_float4(o[6], o[7], o[8], o[9]);
      *(float4*)(rp + 32) = make_float4(o[10], o[11], o[12], o[13]);
      *(float4*)(rp + 36) = make_float4(o[14], o[15], o[16], o[17]);
    }
  }
}

// ---- V-blur in place (rows 0..15 written), reg-buffered, 1/3 folded at write.
// ALL threads must call (internal barrier).
template <int NP>
__device__ inline void vblur_planes(float* lds, int tid,
                                    const float* __restrict__ gw) {
  float4 acc[8];
  bool valid = tid < NP * 18;
  int f = 0, ccg = 0, half = 0;
  if (valid) {
    f = tid / 18;
    int rr = tid - f * 18;
    ccg = 1 + (rr >> 1);
    half = rr & 1;
    const float* cp = lds + f * TPP + (half * 8) * TPITCH + ccg * 4;
#pragma unroll
    for (int i = 0; i < 8; ++i) acc[i] = make_float4(0.f, 0.f, 0.f, 0.f);
#pragma unroll
    for (int j = 0; j < 18; ++j) {
      float4 vv = *(const float4*)(cp + j * TPITCH);
#pragma unroll
      for (int r2 = 0; r2 < 8; ++r2) {
        int d = j - r2;
        if (d >= 0 && d < 11) {
          float gg = gw[d];
          acc[r2].x += gg * vv.x;
          acc[r2].y += gg * vv.y;
          acc[r2].z += gg * vv.z;
          acc[r2].w += gg * vv.w;
        }
      }
    }
  }
  __syncthreads();
  if (valid) {
    const float TH = 1.f / 3.f;
    float* wp = lds + f * TPP + (half * 8) * TPITCH + ccg * 4;
#pragma unroll
    for (int r2 = 0; r2 < 8; ++r2)
      *(float4*)(wp + r2 * TPITCH) =
          make_float4(acc[r2].x * TH, acc[r2].y * TH,
                      acc[r2].z * TH, acc[r2].w * TH);
  }
}

// Guarded 2x float2 load into 4 named scalars (pre-zeroed by caller).
#define LD4S(SRC, A, B, C, D) do {                                        \
    if (aok0) { float2 _t = *(const float2*)((SRC) + arbase + agx);       \
                A = _t.x; B = _t.y; }                                     \
    if (aok2) { float2 _t = *(const float2*)((SRC) + arbase + agx + 2);   \
                C = _t.x; D = _t.y; }                                     \
  } while (0)

// Load one exposure (3 channels), write {Sy, Sy2, Sxy} planes at base pb.
#define DO_EXPOSURE(YB, pb) do {                                          \
    float a0=0.f,a1=0.f,a2=0.f,a3=0.f;                                    \
    float b0=0.f,b1=0.f,b2=0.f,b3=0.f;                                    \
    float c0=0.f,c1=0.f,c2=0.f,c3=0.f;                                    \
    LD4S((YB),             a0, a1, a2, a3);                               \
    LD4S((YB) + PLANE,     b0, b1, b2, b3);                               \
    LD4S((YB) + 2*PLANE,   c0, c1, c2, c3);                               \
    *(float4*)(lds + (pb)*TPP + aob) =                                    \
        make_float4(a0+b0+c0, a1+b1+c1, a2+b2+c2, a3+b3+c3);              \
    *(float4*)(lds + ((pb)+1)*TPP + aob) =                                \
        make_float4(a0*a0+b0*b0+c0*c0, a1*a1+b1*b1+c1*c1,                 \
                    a2*a2+b2*b2+c2*c2, a3*a3+b3*b3+c3*c3);                \
    *(float4*)(lds + ((pb)+2)*TPP + aob) =                                \
        make_float4(xv00*a0+xv10*b0+xv20*c0, xv01*a1+xv11*b1+xv21*c1,     \
                    xv02*a2+xv12*b2+xv22*c2, xv03*a3+xv13*b3+xv23*c3);    \
  } while (0)

// Fusion update for exposure kk with blurred planes at base pb.
#define FUSE_K(kk, pb) do {                                               \
    float muY  = lds[(pb)*TPP + doff];                                    \
    float sigY = lds[((pb)+1)*TPP + doff] - muY*muY;                      \
    float sXY  = lds[((pb)+2)*TPP + doff] - muX*muY;                      \
    float cs = (2.f*sXY + 9e-4f) / (sigX + sigY + 9e-4f);                 \
    if (sigY > best_sig) { best_sig = sigY; best_cs = cs; }               \
    float dm = muY - 0.5f;                                                \
    float lL = expf(-dm*dm*12.5f);                                        \
    float LY = (float)lG[kk] * lL;                                        \
    num += LY*muY; den += LY;                                             \
  } while (0)

// k2 v6: two passes over 8 LDS planes (36.6 KB). X in 12 named scalar VGPRs.
// No lambdas / address-cast vectors in hot path (scratch-spill fix).
__global__ __launch_bounds__(512, 6) void k2_main(const float* __restrict__ X,
                                                  const float* __restrict__ Ys,
                                                  const float* __restrict__ gwin,
                                                  const double* __restrict__ lG,
                                                  double* __restrict__ qpart) {
  __shared__ float4 lds4[8 * TPP / 4];     // 9152 floats = 36608 B
  __shared__ double qred[8];
  float* lds = (float*)lds4;

  int bid = blockIdx.x;
  int wg = (bid & 7) * 1024 + (bid >> 3);  // XCD-compact swizzle
  int tX = wg & 63, tY = wg >> 6;
  int x0 = tX * 32, y0 = tY * 16;
  int tid = threadIdx.x;

  // ---- A-task geometry (tid < 286) ----
  int arow = tid / 11, ag = tid - arow * 11;
  int agy = y0 - 5 + arow;
  int agx = x0 - 6 + 4 * ag;
  bool aactive = tid < 286;
  bool arok = aactive && ((unsigned)agy < (unsigned)HH);
  bool aok0 = arok && ((unsigned)agx < (unsigned)WW);
  bool aok2 = arok && ((unsigned)(agx + 2) < (unsigned)WW);
  size_t arbase = arok ? (size_t)agy * WW : 0;
  int aob = arow * TPITCH + 4 * ag;

  // per-pixel persistent fusion state
  int dty = tid >> 5, dtx = tid & 31;
  int doff = dty * TPITCH + 6 + dtx;
  float muX = 0.f, sigX = 0.f;
  float best_sig = -1e30f, best_cs = 0.f;
  float num = 0.f, den = 0.f;

  // X held in 12 named scalar registers across both passes
  float xv00=0.f,xv01=0.f,xv02=0.f,xv03=0.f;
  float xv10=0.f,xv11=0.f,xv12=0.f,xv13=0.f;
  float xv20=0.f,xv21=0.f,xv22=0.f,xv23=0.f;

  // ================= pass 1: Sx, Sx2, k0, k1 =================
  if (aactive) {
    LD4S(X,             xv00, xv01, xv02, xv03);
    LD4S(X + PLANE,     xv10, xv11, xv12, xv13);
    LD4S(X + 2*PLANE,   xv20, xv21, xv22, xv23);
    *(float4*)(lds + 0 * TPP + aob) =
        make_float4(xv00+xv10+xv20, xv01+xv11+xv21,
                    xv02+xv12+xv22, xv03+xv13+xv23);
    *(float4*)(lds + 1 * TPP + aob) =
        make_float4(xv00*xv00+xv10*xv10+xv20*xv20,
                    xv01*xv01+xv11*xv11+xv21*xv21,
                    xv02*xv02+xv12*xv12+xv22*xv22,
                    xv03*xv03+xv13*xv13+xv23*xv23);
    DO_EXPOSURE(Ys, 2);
    DO_EXPOSURE(Ys + (size_t)3 * PLANE, 5);
  }
  __syncthreads();
  hblur_planes<8>(lds, tid, gwin);
  __syncthreads();
  vblur_planes<8>(lds, tid, gwin);
  __syncthreads();
  muX  = lds[0 * TPP + doff];
  sigX = lds[1 * TPP + doff] - muX * muX;
  FUSE_K(0, 2);
  FUSE_K(1, 5);
  __syncthreads();

  // ================= pass 2: k2, k3 =================
  if (aactive) {
    DO_EXPOSURE(Ys + (size_t)6 * PLANE, 0);
    DO_EXPOSURE(Ys + (size_t)9 * PLANE, 3);
  }
  __syncthreads();
  hblur_planes<6>(lds, tid, gwin);
  __syncthreads();
  vblur_planes<6>(lds, tid, gwin);
  __syncthreads();
  FUSE_K(2, 0);
  FUSE_K(3, 3);

  // ---- finalize ----
  {
    float muYw = num / den;
    float l = (2.f * muX * muYw + 1e-4f) / (muX * muX + muYw * muYw + 1e-4f);
    double v = (double)(l * best_cs);
    v = wave_red(v);
    int lane = tid & 63, wid = tid >> 6;
    if (lane == 0) qred[wid] = v;
    __syncthreads();
    if (tid == 0) {
      double t = 0.0;
#pragma unroll
      for (int i = 0; i < 8; ++i) t += qred[i];
      qpart[blockIdx.x] = t;
    }
  }
}

__global__ __launch_bounds__(512) void k3_final(const double* __restrict__ qpart,
                                                float* __restrict__ out) {
  double acc = 0.0;
  for (int i = threadIdx.x; i < 8192; i += 512) acc += qpart[i];
  acc = wave_red(acc);
  __shared__ double red[8];
  int lane = threadIdx.x & 63, wid = threadIdx.x >> 6;
  if (lane == 0) red[wid] = acc;
  __syncthreads();
  if (threadIdx.x == 0)
    out[0] = (float)((red[0] + red[1] + red[2] + red[3] +
                      red[4] + red[5] + red[6] + red[7]) * (1.0 / 4194304.0));
}

extern "C" void kernel_launch(void* const* d_in, const int* in_sizes, int n_in,
                              void* d_out, int out_size, void* d_ws, size_t ws_size,
                              hipStream_t stream) {
  const float* X  = (const float*)d_in[0];
  const float* Ys = (const float*)d_in[1];
  char* ws = (char*)d_ws;
  float*  gwin   = (float*)(ws + 0);
  double* lG     = (double*)(ws + 128);
  double* lYpart = (double*)(ws + 256);
  double* qpart  = (double*)(ws + 17408);
  float* out = (float*)d_out;

  hipLaunchKernelGGL(k0_window, dim3(1), dim3(64), 0, stream, gwin);
  hipLaunchKernelGGL(k1_lY, dim3(2112), dim3(256), 0, stream, Ys, gwin, lYpart);
  hipLaunchKernelGGL(k2a_lG, dim3(1), dim3(256), 0, stream, lYpart, lG);
  hipLaunchKernelGGL(k2_main, dim3(8192), dim3(512), 0, stream, X, Ys, gwin, lG, qpart);
  hipLaunchKernelGGL(k3_final, dim3(1), dim3(512), 0, stream, qpart, out);
}

// Round 7
// 188.842 us; speedup vs baseline: 1.1409x; 1.1409x over previous
//
#include <hip/hip_runtime.h>
#include <math.h>

#define HH 2048
#define WW 2048
#define PLANE 4194304        // HH*WW
#define TROWS 25             // halo rows for 15-row output tile
#define TPITCH 44
#define TPP (TROWS*TPITCH)   // 1100 floats per plane
#define NBLK 8768            // 64 x-tiles * 137 y-tiles
#define CHUNK 1096           // NBLK / 8

// ws layout (bytes):
// 0     : float gwin[11]
// 64    : float gwin3[11]
// 128   : double lG[4]
// 256   : double lYpart[4*528]   (16896 B)
// 17408 : double qpart[8768]     (70144 B)

__device__ inline double wave_red(double v) {
#pragma unroll
  for (int o = 32; o > 0; o >>= 1) v += __shfl_down(v, o, 64);
  return v;
}

__global__ void k0_window(float* gwin, float* gwin3) {
  if (threadIdx.x == 0) {
    double e[11], s = 0.0;
    double sig = 11.0 / 6.0;
    for (int i = 0; i < 11; ++i) {
      double x = (double)(i - 5);
      e[i] = exp(-(x * x) / (2.0 * sig * sig));
      s += e[i];
    }
    for (int i = 0; i < 11; ++i) {
      gwin[i]  = (float)(e[i] / s);
      gwin3[i] = (float)(e[i] / (3.0 * s));
    }
  }
}

// k1: lY partial sums (unchanged; ~18 us).
__global__ __launch_bounds__(256) void k1_lY(const float* __restrict__ Ys,
                                             const float* __restrict__ gwin,
                                             double* __restrict__ lYpart) {
  int bid = blockIdx.x;
  int tid = threadIdx.x;
  double acc = 0.0;
  __shared__ float P[12];
  __shared__ double red[4];

  if (bid < 2048) {
    const float4* __restrict__ p = (const float4*)Ys;
    int base = bid * 6144 + tid;
#pragma unroll 1
    for (int gblk = 0; gblk < 3; ++gblk) {
      float ax = 0.f, ay = 0.f;
#pragma unroll
      for (int u = 0; u < 8; ++u) {
        float4 v = p[base + (gblk * 8 + u) * 256];
        ax += v.x + v.z;
        ay += v.y + v.w;
      }
      acc += (double)(ax + ay);
    }
  } else {
    int b = bid - 2048;             // 0..63
    int k = b >> 4, sub = b & 15;
    if (tid == 0) {
      float s = 0.f;
      for (int i = 0; i < 12; ++i) { P[i] = s; if (i < 11) s += gwin[i]; }
    }
    __syncthreads();
    const float4* __restrict__ Yk4 = (const float4*)(Ys + (size_t)k * 3 * PLANE);
    auto covP = [&](int r) -> float {
      if (r >= 5 && r <= 2042) return 1.0f;
      int dhi = r + 5; if (dhi > 10) dhi = 10;
      int dlo = r - 2042; if (dlo < 0) dlo = 0;
      return P[dhi + 1] - P[dlo];
    };
#pragma unroll 1
    for (int t = sub * 256 + tid; t < 39816; t += 4096) {
      int ch, row, g4;
      if (t < 15360) {
        ch = t / 5120;
        int r = (t % 5120) / 512;
        g4 = t & 511;
        row = (r < 5) ? r : r + 2038;
      } else {
        int u = t - 15360;
        ch = u / 8152;
        int rem = u % 8152;
        row = 5 + (rem >> 2);
        int gi = rem & 3;
        g4 = (gi < 2) ? gi : 508 + gi;
      }
      float4 v = Yk4[ch * 1048576 + row * 512 + g4];
      float cy = covP(row);
      int x0 = g4 << 2;
      float w0 = cy * covP(x0)     - 1.0f;
      float w1 = cy * covP(x0 + 1) - 1.0f;
      float w2 = cy * covP(x0 + 2) - 1.0f;
      float w3 = cy * covP(x0 + 3) - 1.0f;
      acc += (double)(w0 * v.x + w1 * v.y + w2 * v.z + w3 * v.w);
    }
  }

  acc = wave_red(acc);
  int lane = tid & 63, wid = tid >> 6;
  __syncthreads();
  if (lane == 0) red[wid] = acc;
  __syncthreads();
  if (tid == 0) {
    double tot = red[0] + red[1] + red[2] + red[3];
    if (bid < 2048) {
      int k = bid >> 9;
      lYpart[k * 528 + (bid & 511)] = tot;
    } else {
      int b = bid - 2048;
      lYpart[(b >> 4) * 528 + 512 + (b & 15)] = tot;
    }
  }
}

__global__ __launch_bounds__(256) void k2a_lG(const double* __restrict__ lYpart,
                                              double* __restrict__ lG) {
  __shared__ double red[4];
  for (int k = 0; k < 4; ++k) {
    const double* p = lYpart + k * 528;
    double v = p[threadIdx.x] + p[256 + threadIdx.x];
    if (threadIdx.x < 16) v += p[512 + threadIdx.x];
    v = wave_red(v);
    int lane = threadIdx.x & 63, wid = threadIdx.x >> 6;
    if (lane == 0) red[wid] = v;
    __syncthreads();
    if (threadIdx.x == 0) {
      double tot = red[0] + red[1] + red[2] + red[3];
      double lY = tot * (1.0 / 12582912.0);
      double d = lY - 0.5;
      lG[k] = exp(-(d * d) / 0.08);
    }
    __syncthreads();
  }
}

// ---- r3-verbatim stage bodies as macros (plane count NP) ----
// H-blur in place: one thread per (field,row), w[44] snapshot.
#define HB_BODY(NP) do {                                                   \
    if (tid < (NP) * TROWS) {                                              \
      int hf = tid / TROWS, hrow = tid - hf * TROWS;                       \
      float* rp = lds + hf * TPP + hrow * TPITCH;                          \
      float w[44];                                                         \
      _Pragma("unroll")                                                    \
      for (int j = 0; j < 11; ++j) {                                       \
        float4 w4 = *(const float4*)(rp + 4 * j);                          \
        w[4*j] = w4.x; w[4*j+1] = w4.y; w[4*j+2] = w4.z; w[4*j+3] = w4.w;  \
      }                                                                    \
      _Pragma("unroll")                                                    \
      for (int gq = 0; gq < 9; ++gq) {                                     \
        float4 o4;                                                         \
        _Pragma("unroll")                                                  \
        for (int e = 0; e < 4; ++e) {                                      \
          int pp = 4 * gq + e;                                             \
          float s = 0.f;                                                   \
          _Pragma("unroll")                                                \
          for (int d = 0; d < 11; ++d) {                                   \
            int wi = pp - 1 + d;                                           \
            if (wi < 0) wi = 0;                                            \
            if (wi > 43) wi = 43;                                          \
            s += g[d] * w[wi];                                             \
          }                                                                \
          ((float*)&o4)[e] = s;                                            \
        }                                                                  \
        *(float4*)(rp + 4 + 4 * gq) = o4;                                  \
      }                                                                    \
    }                                                                      \
  } while (0)

// V-blur in place, reg-buffered, internal barrier (ALL threads reach it).
// Halves at row offsets 0 and 7 (row 7 double-written with identical value).
#define VB_BODY(NP) do {                                                   \
    float4 vacc[8];                                                        \
    bool vvalid = tid < (NP) * 18;                                         \
    int vf = 0, vcg = 0, vrb = 0;                                          \
    if (vvalid) {                                                          \
      vf = tid / 18;                                                       \
      int rr = tid - vf * 18;                                              \
      vcg = 1 + (rr >> 1);                                                 \
      vrb = (rr & 1) * 7;                                                  \
      const float* cp = lds + vf * TPP + vrb * TPITCH + vcg * 4;           \
      _Pragma("unroll")                                                    \
      for (int i = 0; i < 8; ++i) vacc[i] = make_float4(0.f, 0.f, 0.f, 0.f); \
      _Pragma("unroll")                                                    \
      for (int j = 0; j < 18; ++j) {                                       \
        float4 vv = *(const float4*)(cp + j * TPITCH);                     \
        _Pragma("unroll")                                                  \
        for (int r2 = 0; r2 < 8; ++r2) {                                   \
          int d = j - r2;                                                  \
          if (d >= 0 && d < 11) {                                          \
            vacc[r2].x += g3[d] * vv.x;                                    \
            vacc[r2].y += g3[d] * vv.y;                                    \
            vacc[r2].z += g3[d] * vv.z;                                    \
            vacc[r2].w += g3[d] * vv.w;                                    \
          }                                                                \
        }                                                                  \
      }                                                                    \
    }                                                                      \
    __syncthreads();                                                       \
    if (vvalid) {                                                          \
      float* wp = lds + vf * TPP + vrb * TPITCH + vcg * 4;                 \
      _Pragma("unroll")                                                    \
      for (int r2 = 0; r2 < 8; ++r2)                                       \
        *(float4*)(wp + r2 * TPITCH) = vacc[r2];                           \
    }                                                                      \
  } while (0)

// k2 v7: r3 monolith, 32x15 tile, X phase first (muX/sigX -> 2 regs),
// then 12 exposure planes in 52.8 KB LDS -> 3 blocks/CU.
__global__ __launch_bounds__(512, 6) void k2_main(const float* __restrict__ X,
                                                  const float* __restrict__ Ys,
                                                  const float* __restrict__ gwin,
                                                  const float* __restrict__ gwin3,
                                                  const double* __restrict__ lG,
                                                  double* __restrict__ qpart) {
  __shared__ float4 lds4[12 * TPP / 4];    // 13200 floats = 52800 B
  __shared__ double qred[8];
  float* lds = (float*)lds4;

  int bid = blockIdx.x;
  int wg = (bid & 7) * CHUNK + (bid >> 3);  // XCD-compact swizzle (bijective)
  int tX = wg & 63, tY = wg >> 6;           // 64 x-tiles, 137 y-tiles
  int x0 = tX * 32, y0 = tY * 15;
  int tid = threadIdx.x;

  float g[11], g3[11];
#pragma unroll
  for (int i = 0; i < 11; ++i) { g[i] = gwin[i]; g3[i] = gwin3[i]; }

  // ---- A-task geometry (tid < 275 = 25 rows x 11 float4-groups) ----
  int arow = tid / 11, ag = tid - arow * 11;
  int agy = y0 - 5 + arow;
  int agx = x0 - 6 + 4 * ag;
  bool aactive = tid < 275;
  bool arok = aactive && ((unsigned)agy < (unsigned)HH);
  size_t arbase = arok ? (size_t)agy * WW : 0;
  int aob = arow * TPITCH + 4 * ag;

  // ---- D geometry ----
  int dty = tid >> 5, dtx = tid & 31;
  int doff = dty * TPITCH + 6 + dtx;
  bool dvalid = (dty < 15) && (y0 + dty < HH);

  // ================= phase 1: X -> muX, sigX =================
  if (aactive) {
    float v[3][4];
#pragma unroll
    for (int p = 0; p < 3; ++p) {
      const float* src = X + (size_t)p * PLANE;
#pragma unroll
      for (int h = 0; h < 2; ++h) {
        int xx = agx + 2 * h;
        float2 w2 = make_float2(0.f, 0.f);
        if (arok && (unsigned)xx < (unsigned)WW)
          w2 = *(const float2*)(src + arbase + xx);
        v[p][2 * h] = w2.x;
        v[p][2 * h + 1] = w2.y;
      }
    }
    float4 sx, sx2;
#pragma unroll
    for (int e = 0; e < 4; ++e) {
      float s0 = v[0][e], s1 = v[1][e], s2 = v[2][e];
      ((float*)&sx)[e]  = s0 + s1 + s2;
      ((float*)&sx2)[e] = s0 * s0 + s1 * s1 + s2 * s2;
    }
    *(float4*)(lds + 0 * TPP + aob) = sx;
    *(float4*)(lds + 1 * TPP + aob) = sx2;
  }
  __syncthreads();
  HB_BODY(2);
  __syncthreads();
  VB_BODY(2);
  __syncthreads();
  float muX  = lds[0 * TPP + doff];
  float sigX = lds[1 * TPP + doff] - muX * muX;
  __syncthreads();

  // ================= phase 2: 4 exposures, 12 planes =================
  if (aactive) {
    float v[15][4];
#pragma unroll
    for (int p = 0; p < 15; ++p) {
      const float* src = (p < 3) ? (X + (size_t)p * PLANE)
                                 : (Ys + (size_t)(p - 3) * PLANE);
#pragma unroll
      for (int h = 0; h < 2; ++h) {
        int xx = agx + 2 * h;
        float2 w2 = make_float2(0.f, 0.f);
        if (arok && (unsigned)xx < (unsigned)WW)
          w2 = *(const float2*)(src + arbase + xx);
        v[p][2 * h] = w2.x;
        v[p][2 * h + 1] = w2.y;
      }
    }
#pragma unroll
    for (int k = 0; k < 4; ++k) {
      float4 sy, sy2, sxy;
#pragma unroll
      for (int e = 0; e < 4; ++e) {
        float ya = v[3 + 3 * k][e], yb = v[4 + 3 * k][e], yc = v[5 + 3 * k][e];
        ((float*)&sy)[e]  = ya + yb + yc;
        ((float*)&sy2)[e] = ya * ya + yb * yb + yc * yc;
        ((float*)&sxy)[e] = v[0][e] * ya + v[1][e] * yb + v[2][e] * yc;
      }
      *(float4*)(lds + (3 * k + 0) * TPP + aob) = sy;
      *(float4*)(lds + (3 * k + 1) * TPP + aob) = sy2;
      *(float4*)(lds + (3 * k + 2) * TPP + aob) = sxy;
    }
  }
  __syncthreads();
  HB_BODY(12);
  __syncthreads();
  VB_BODY(12);
  __syncthreads();

  // ---- stage D: per-pixel fusion + block reduction ----
  {
    float b[12];
#pragma unroll
    for (int f = 0; f < 12; ++f) b[f] = lds[f * TPP + doff];
    float muX2 = muX * muX;
    float num = 0.f, den = 0.f;
    float best_sig = -1e30f, best_cs = 0.f;
#pragma unroll
    for (int k = 0; k < 4; ++k) {
      float muY  = b[3 * k];
      float sigY = b[3 * k + 1] - muY * muY;
      float sXY  = b[3 * k + 2] - muX * muY;
      float cs = (2.f * sXY + 9e-4f) / (sigX + sigY + 9e-4f);
      if (sigY > best_sig) { best_sig = sigY; best_cs = cs; }
      float dm = muY - 0.5f;
      float lL = expf(-dm * dm * 12.5f);
      float LY = (float)lG[k] * lL;
      num += LY * muY;
      den += LY;
    }
    float muYw = num / den;
    float l = (2.f * muX * muYw + 1e-4f) / (muX2 + muYw * muYw + 1e-4f);
    double v = dvalid ? (double)(l * best_cs) : 0.0;
    v = wave_red(v);
    int lane = tid & 63, wid = tid >> 6;
    if (lane == 0) qred[wid] = v;
    __syncthreads();
    if (tid == 0) {
      double t = 0.0;
#pragma unroll
      for (int i = 0; i < 8; ++i) t += qred[i];
      qpart[blockIdx.x] = t;
    }
  }
}

__global__ __launch_bounds__(512) void k3_final(const double* __restrict__ qpart,
                                                float* __restrict__ out) {
  double acc = 0.0;
  for (int i = threadIdx.x; i < NBLK; i += 512) acc += qpart[i];
  acc = wave_red(acc);
  __shared__ double red[8];
  int lane = threadIdx.x & 63, wid = threadIdx.x >> 6;
  if (lane == 0) red[wid] = acc;
  __syncthreads();
  if (threadIdx.x == 0)
    out[0] = (float)((red[0] + red[1] + red[2] + red[3] +
                      red[4] + red[5] + red[6] + red[7]) * (1.0 / 4194304.0));
}

extern "C" void kernel_launch(void* const* d_in, const int* in_sizes, int n_in,
                              void* d_out, int out_size, void* d_ws, size_t ws_size,
                              hipStream_t stream) {
  const float* X  = (const float*)d_in[0];
  const float* Ys = (const float*)d_in[1];
  char* ws = (char*)d_ws;
  float*  gwin   = (float*)(ws + 0);
  float*  gwin3  = (float*)(ws + 64);
  double* lG     = (double*)(ws + 128);
  double* lYpart = (double*)(ws + 256);
  double* qpart  = (double*)(ws + 17408);
  float* out = (float*)d_out;

  hipLaunchKernelGGL(k0_window, dim3(1), dim3(64), 0, stream, gwin, gwin3);
  hipLaunchKernelGGL(k1_lY, dim3(2112), dim3(256), 0, stream, Ys, gwin, lYpart);
  hipLaunchKernelGGL(k2a_lG, dim3(1), dim3(256), 0, stream, lYpart, lG);
  hipLaunchKernelGGL(k2_main, dim3(NBLK), dim3(512), 0, stream, X, Ys, gwin, gwin3, lG, qpart);
  hipLaunchKernelGGL(k3_final, dim3(1), dim3(512), 0, stream, qpart, out);
}

// Round 8
// 163.225 us; speedup vs baseline: 1.3199x; 1.1569x over previous
//
#include <hip/hip_runtime.h>
#include <math.h>

#define HH 2048
#define WW 2048
#define PLANE 4194304        // HH*WW
#define PITCH 43             // odd pitch: conflict-free b32 LDS (r1/r2-proven)
#define PP (26*PITCH)        // per-field plane size (floats)

// ws layout (bytes):
// 0     : float gwin[11]
// 64    : float gwin3[11]
// 128   : double lG[4]
// 256   : double lYpart[4*528]   (16896 B)
// 17408 : double qpart[8192]     (65536 B)

__device__ inline double wave_red(double v) {
#pragma unroll
  for (int o = 32; o > 0; o >>= 1) v += __shfl_down(v, o, 64);
  return v;
}

__global__ void k0_window(float* gwin, float* gwin3) {
  if (threadIdx.x == 0) {
    double e[11], s = 0.0;
    double sig = 11.0 / 6.0;
    for (int i = 0; i < 11; ++i) {
      double x = (double)(i - 5);
      e[i] = exp(-(x * x) / (2.0 * sig * sig));
      s += e[i];
    }
    for (int i = 0; i < 11; ++i) {
      gwin[i]  = (float)(e[i] / s);
      gwin3[i] = (float)(e[i] / (3.0 * s));
    }
  }
}

// k1: lY partial sums (r3-era, ~18 us).
__global__ __launch_bounds__(256) void k1_lY(const float* __restrict__ Ys,
                                             const float* __restrict__ gwin,
                                             double* __restrict__ lYpart) {
  int bid = blockIdx.x;
  int tid = threadIdx.x;
  double acc = 0.0;
  __shared__ float P[12];
  __shared__ double red[4];

  if (bid < 2048) {
    const float4* __restrict__ p = (const float4*)Ys;
    int base = bid * 6144 + tid;
#pragma unroll 1
    for (int gblk = 0; gblk < 3; ++gblk) {
      float ax = 0.f, ay = 0.f;
#pragma unroll
      for (int u = 0; u < 8; ++u) {
        float4 v = p[base + (gblk * 8 + u) * 256];
        ax += v.x + v.z;
        ay += v.y + v.w;
      }
      acc += (double)(ax + ay);
    }
  } else {
    int b = bid - 2048;             // 0..63
    int k = b >> 4, sub = b & 15;
    if (tid == 0) {
      float s = 0.f;
      for (int i = 0; i < 12; ++i) { P[i] = s; if (i < 11) s += gwin[i]; }
    }
    __syncthreads();
    const float4* __restrict__ Yk4 = (const float4*)(Ys + (size_t)k * 3 * PLANE);
    auto covP = [&](int r) -> float {
      if (r >= 5 && r <= 2042) return 1.0f;
      int dhi = r + 5; if (dhi > 10) dhi = 10;
      int dlo = r - 2042; if (dlo < 0) dlo = 0;
      return P[dhi + 1] - P[dlo];
    };
#pragma unroll 1
    for (int t = sub * 256 + tid; t < 39816; t += 4096) {
      int ch, row, g4;
      if (t < 15360) {
        ch = t / 5120;
        int r = (t % 5120) / 512;
        g4 = t & 511;
        row = (r < 5) ? r : r + 2038;
      } else {
        int u = t - 15360;
        ch = u / 8152;
        int rem = u % 8152;
        row = 5 + (rem >> 2);
        int gi = rem & 3;
        g4 = (gi < 2) ? gi : 508 + gi;
      }
      float4 v = Yk4[ch * 1048576 + row * 512 + g4];
      float cy = covP(row);
      int x0 = g4 << 2;
      float w0 = cy * covP(x0)     - 1.0f;
      float w1 = cy * covP(x0 + 1) - 1.0f;
      float w2 = cy * covP(x0 + 2) - 1.0f;
      float w3 = cy * covP(x0 + 3) - 1.0f;
      acc += (double)(w0 * v.x + w1 * v.y + w2 * v.z + w3 * v.w);
    }
  }

  acc = wave_red(acc);
  int lane = tid & 63, wid = tid >> 6;
  __syncthreads();
  if (lane == 0) red[wid] = acc;
  __syncthreads();
  if (tid == 0) {
    double tot = red[0] + red[1] + red[2] + red[3];
    if (bid < 2048) {
      int k = bid >> 9;
      lYpart[k * 528 + (bid & 511)] = tot;
    } else {
      int b = bid - 2048;
      lYpart[(b >> 4) * 528 + 512 + (b & 15)] = tot;
    }
  }
}

__global__ __launch_bounds__(256) void k2a_lG(const double* __restrict__ lYpart,
                                              double* __restrict__ lG) {
  __shared__ double red[4];
  for (int k = 0; k < 4; ++k) {
    const double* p = lYpart + k * 528;
    double v = p[threadIdx.x] + p[256 + threadIdx.x];
    if (threadIdx.x < 16) v += p[512 + threadIdx.x];
    v = wave_red(v);
    int lane = threadIdx.x & 63, wid = threadIdx.x >> 6;
    if (lane == 0) red[wid] = v;
    __syncthreads();
    if (threadIdx.x == 0) {
      double tot = red[0] + red[1] + red[2] + red[3];
      double lY = tot * (1.0 / 12582912.0);
      double d = lY - 0.5;
      lG[k] = exp(-(d * d) / 0.08);
    }
    __syncthreads();
  }
}

// k2: ROUND-1 kernel verbatim. 32x16 output tile, 42x26 halo, 14 product
// fields, in-place separable blur in LDS (pitch 43, b32, conflict-free),
// per-pixel fusion, block partial of l*cs.
__global__ __launch_bounds__(512) void k2_main(const float* __restrict__ X,
                                               const float* __restrict__ Ys,
                                               const float* __restrict__ gwin,
                                               const float* __restrict__ gwin3,
                                               const double* __restrict__ lG,
                                               double* __restrict__ qpart) {
  __shared__ float prod[14 * PP];   // 62,608 B
  __shared__ double qred[8];

  int bid = blockIdx.x;
  // XCD-compact swizzle (8192 % 8 == 0, bijective): x-adjacent tiles share L2
  int wg = (bid & 7) * 1024 + (bid >> 3);
  int tX = wg & 63, tY = wg >> 6;     // 64 x-tiles, 128 y-tiles
  int x0 = tX * 32, y0 = tY * 16;
  int tid = threadIdx.x;

  float g[11], g3[11];
#pragma unroll
  for (int i = 0; i < 11; ++i) { g[i] = gwin[i]; g3[i] = gwin3[i]; }

  // ---- Stage A: channel-collapsed products into LDS planes (halo 42x26) ----
  const size_t PL = (size_t)HH * WW;
  for (int pos = tid; pos < 42 * 26; pos += 512) {
    int py = pos / 42;
    int px = pos - py * 42;
    int gy = y0 - 5 + py;
    int gx = x0 - 5 + px;
    float xv0 = 0.f, xv1 = 0.f, xv2 = 0.f;
    float yv[12];
#pragma unroll
    for (int j = 0; j < 12; ++j) yv[j] = 0.f;
    if ((unsigned)gy < (unsigned)HH && (unsigned)gx < (unsigned)WW) {
      size_t off = (size_t)gy * WW + gx;
      xv0 = X[off];
      xv1 = X[off + PL];
      xv2 = X[off + 2 * PL];
#pragma unroll
      for (int j = 0; j < 12; ++j) yv[j] = Ys[off + (size_t)j * PL];
    }
    int o = py * PITCH + px;
    prod[0 * PP + o] = xv0 + xv1 + xv2;
    prod[1 * PP + o] = xv0 * xv0 + xv1 * xv1 + xv2 * xv2;
#pragma unroll
    for (int k = 0; k < 4; ++k) {
      float a = yv[3 * k], b = yv[3 * k + 1], c = yv[3 * k + 2];
      prod[(2 + k) * PP + o]  = a + b + c;
      prod[(6 + k) * PP + o]  = a * a + b * b + c * c;
      prod[(10 + k) * PP + o] = xv0 * a + xv1 * b + xv2 * c;
    }
  }
  __syncthreads();

  // ---- Stage B: horizontal 11-tap blur, in place, register sliding window ----
  // tasks: 14 fields x 26 rows x 4 groups of 8 outputs = 1456; rows never cross
  // iteration boundaries (512 % 4 == 0), blur is within-row only.
#pragma unroll 1
  for (int it = 0; it < 3; ++it) {
    int t = it * 512 + tid;
    bool valid = t < 1456;
    int f = 0, py = 0, xg = 0;
    float w[18];
    if (valid) {
      f = t / 104;
      int rr = t - f * 104;
      py = rr >> 2;
      xg = (rr & 3) * 8;
      int base = f * PP + py * PITCH + xg;
#pragma unroll
      for (int j = 0; j < 18; ++j) w[j] = prod[base + j];
    }
    __syncthreads();
    if (valid) {
      int base = f * PP + py * PITCH + xg;
#pragma unroll
      for (int o = 0; o < 8; ++o) {
        float s = 0.f;
#pragma unroll
        for (int d = 0; d < 11; ++d) s += g[d] * w[o + d];
        prod[base + o] = s;
      }
    }
    __syncthreads();
  }

  // ---- Stage C: vertical 11-tap blur (taps include /3), thread-per-column ----
  if (tid < 448) {                 // 14 fields x 32 columns
    int f = tid >> 5, tx = tid & 31;
    int base = f * PP + tx;
    float col[26];
#pragma unroll
    for (int py = 0; py < 26; ++py) col[py] = prod[base + py * PITCH];
#pragma unroll
    for (int ty = 0; ty < 16; ++ty) {
      float s = 0.f;
#pragma unroll
      for (int d = 0; d < 11; ++d) s += g3[d] * col[ty + d];
      prod[base + ty * PITCH] = s;
    }
  }
  __syncthreads();

  // ---- Stage D: per-pixel fusion + block reduction ----
  {
    int ty = tid >> 5, tx = tid & 31;   // 512 threads = full 16x32 tile
    int o = ty * PITCH + tx;
    float b[14];
#pragma unroll
    for (int f = 0; f < 14; ++f) b[f] = prod[f * PP + o];
    float muX = b[0];
    float muX2 = muX * muX;
    float sigX = b[1] - muX2;
    float num = 0.f, den = 0.f;
    float best_sig = -1e30f, best_cs = 0.f;
#pragma unroll
    for (int k = 0; k < 4; ++k) {
      float muY  = b[2 + k];
      float sigY = b[6 + k] - muY * muY;
      float sXY  = b[10 + k] - muX * muY;
      float cs = (2.f * sXY + 9e-4f) / (sigX + sigY + 9e-4f);
      if (sigY > best_sig) { best_sig = sigY; best_cs = cs; }  // first-max wins
      float dm = muY - 0.5f;
      float lL = expf(-dm * dm * 12.5f);          // /DENOM_L = *12.5
      float LY = (float)lG[k] * lL;
      num += LY * muY;
      den += LY;
    }
    float muYw = num / den;
    float l = (2.f * muX * muYw + 1e-4f) / (muX2 + muYw * muYw + 1e-4f);
    double v = (double)(l * best_cs);
    v = wave_red(v);
    int lane = tid & 63, wid = tid >> 6;
    if (lane == 0) qred[wid] = v;
    __syncthreads();
    if (tid == 0) {
      double t = 0.0;
#pragma unroll
      for (int i = 0; i < 8; ++i) t += qred[i];
      qpart[blockIdx.x] = t;
    }
  }
}

__global__ __launch_bounds__(512) void k3_final(const double* __restrict__ qpart,
                                                float* __restrict__ out) {
  double acc = 0.0;
  for (int i = threadIdx.x; i < 8192; i += 512) acc += qpart[i];
  acc = wave_red(acc);
  __shared__ double red[8];
  int lane = threadIdx.x & 63, wid = threadIdx.x >> 6;
  if (lane == 0) red[wid] = acc;
  __syncthreads();
  if (threadIdx.x == 0)
    out[0] = (float)((red[0] + red[1] + red[2] + red[3] +
                      red[4] + red[5] + red[6] + red[7]) * (1.0 / 4194304.0));
}

extern "C" void kernel_launch(void* const* d_in, const int* in_sizes, int n_in,
                              void* d_out, int out_size, void* d_ws, size_t ws_size,
                              hipStream_t stream) {
  const float* X  = (const float*)d_in[0];
  const float* Ys = (const float*)d_in[1];
  char* ws = (char*)d_ws;
  float*  gwin   = (float*)(ws + 0);
  float*  gwin3  = (float*)(ws + 64);
  double* lG     = (double*)(ws + 128);
  double* lYpart = (double*)(ws + 256);
  double* qpart  = (double*)(ws + 17408);
  float* out = (float*)d_out;

  hipLaunchKernelGGL(k0_window, dim3(1), dim3(64), 0, stream, gwin, gwin3);
  hipLaunchKernelGGL(k1_lY, dim3(2112), dim3(256), 0, stream, Ys, gwin, lYpart);
  hipLaunchKernelGGL(k2a_lG, dim3(1), dim3(256), 0, stream, lYpart, lG);
  hipLaunchKernelGGL(k2_main, dim3(8192), dim3(512), 0, stream, X, Ys, gwin, gwin3, lG, qpart);
  hipLaunchKernelGGL(k3_final, dim3(1), dim3(512), 0, stream, qpart, out);
}